// Round 10
// baseline (49.676 us; speedup 1.0000x reference)
//
#include <hip/hip_runtime.h>
#include <math.h>

typedef __attribute__((ext_vector_type(8))) __bf16 bf16x8;
typedef __attribute__((ext_vector_type(4))) __bf16 bf16x4;
typedef __attribute__((ext_vector_type(4))) float f32x4;

#define PLANE 16384
#define ROWW 128

// ws float layout:
//   [0, 12288)     kern [b][c][12]  (taps 0..8 + pad, f4-aligned)
//   [12288, 13312) att  [b][128]
//   [13312, 21504) wfrag: 16384 ushorts (bf16). B-operand fragments of conv_w^T:
//                  frag[ot(8)][kc(4)][lane(64)][j(8)] = conv_w[ot*16+(lane&15)][kc*32+8*(lane>>4)+j]

__global__ __launch_bounds__(256) void precompute_kernel(
    const float* __restrict__ altitude,
    const float* __restrict__ W1,
    const float* __restrict__ W2,
    const float* __restrict__ ca_w1,
    const float* __restrict__ ca_w2,
    const float* __restrict__ conv_w,
    float* __restrict__ ws)
{
    int bid = blockIdx.x;
    int b = bid >> 2;          // image
    int q = bid & 3;           // quarter of the kern work
    int t = threadIdx.x;
    __shared__ float alt_s[128];
    __shared__ float feat_s[128];
    __shared__ float a1_s[16];

    if (t < 128) alt_s[t] = altitude[b * 128 + t];
    __syncthreads();

    if (t < 128) {
        float s = 0.f;
        const float* wrow = W1 + t * 128;
        for (int j = 0; j < 128; ++j) s += alt_s[j] * wrow[j];
        feat_s[t] = (s >= 0.f) ? s : 0.1f * s;
    } else if (t < 144 && q == 1) {
        int r = t - 128;
        float s = 0.f;
        const float* wrow = ca_w1 + r * 128;
        for (int j = 0; j < 128; ++j) s += alt_s[j] * wrow[j];
        a1_s[r] = (s >= 0.f) ? s : 0.1f * s;
    }
    __syncthreads();

    // this quarter's slice of the 1152 generated-kernel dots -> [b][c][12]
    for (int i = t; i < 288; i += 256) {
        int m = q * 288 + i;
        float s = 0.f;
        const float* wrow = W2 + m * 128;
        for (int j = 0; j < 128; ++j) s += feat_s[j] * wrow[j];
        int c = m / 9, k = m % 9;
        ws[b * 1536 + c * 12 + k] = s;
    }
    if (q == 1 && t < 128) {
        float s = 0.f;
        const float* wrow = ca_w2 + t * 16;
        for (int r = 0; r < 16; ++r) s += a1_s[r] * wrow[r];
        ws[12288 + b * 128 + t] = 1.f / (1.f + expf(-s));
    }
    if (q == 2 && t < 256) {
        int kc   = t >> 6;
        int lane = t & 63;
        int o  = b * 16 + (lane & 15);
        int cb = kc * 32 + 8 * (lane >> 4);
        bf16x8 v;
        #pragma unroll
        for (int j = 0; j < 8; ++j)
            v[j] = (__bf16)conv_w[o * 128 + cb + j];
        ushort* wf = (ushort*)(ws + 13312);
        *reinterpret_cast<bf16x8*>(wf + ((size_t)(b * 4 + kc) * 64 + lane) * 8) = v;
    }
}

// Block = 2 output rows x 128 px x 128 ch. Phase 1 reads 4 CONSECUTIVE rows
// per channel; loads grouped 2-channels-deep (16 float4 in flight) and pinned
// with asm keep-alives so the compiler cannot re-sink them (latency hiding).
__global__ __launch_bounds__(512, 2) void fused_kernel(
    const float* __restrict__ x,
    const float* __restrict__ conv_b,
    const float* __restrict__ ws,
    float* __restrict__ out)
{
    const float* __restrict__ kern_w = ws;
    const float* __restrict__ att_w  = ws + 12288;
    const ushort* __restrict__ wfrag = (const ushort*)(ws + 13312);

    int bid = blockIdx.x;
    int b  = bid & 7;          // XCD swizzle: each XCD streams one batch image
    int rb = bid >> 3;         // row-pair 0..63
    int h0 = rb * 2;

    // two row-planes: dwT[row][px][c] bf16, px stride 136 ushorts;
    // c in 16 vblocks of 8; vblock v at slot (v ^ pg); read chunk ^ (px>>3).
    __shared__ __align__(16) ushort dwT[2][128 * 136];
    __shared__ __align__(16) float ktaps[128 * 12];   // [c][12] taps

    int t = threadIdx.x;
    const float* __restrict__ xb = x + (size_t)b * 128 * PLANE;

    for (int i = t; i < 384; i += 512) {
        float4 v = *(const float4*)(kern_w + b * 1536 + i * 4);
        *(float4*)(&ktaps[i * 4]) = v;
    }
    __syncthreads();

    // ---------------- Phase 1: depthwise 3x3 + ReLU (2 rows) -> dwT ----------------
    {
        int pg = t & 15;           // 8-px group (full 128-px row)
        int cg = t >> 4;           // 4-ch group, cg 0..31
        int gp0 = pg * 8;
        int c0 = cg * 4;

        float mL = (pg > 0)  ? 1.f : 0.f;
        float mR = (pg < 15) ? 1.f : 0.f;
        float mTop = (rb > 0)  ? 1.f : 0.f;   // staged row 0 validity
        float mBot = (rb < 63) ? 1.f : 0.f;   // staged row 3 validity
        int r0 = (rb > 0)  ? h0 - 1 : h0;     // clamped (tap-masked anyway)
        int r3 = (rb < 63) ? h0 + 2 : h0;

        bf16x4 bv[2][8];   // [row][pxj] -> 4 bf16 along c; literal indices only

#define DW_LOAD(CI)                                                        \
        const float* q_##CI  = xb + (size_t)(c0 + CI) * PLANE;             \
        const float* p0_##CI = q_##CI + r0 * ROWW + gp0;                   \
        const float* p1_##CI = q_##CI + h0 * ROWW + gp0;                   \
        const float* p2_##CI = q_##CI + (h0 + 1) * ROWW + gp0;             \
        const float* p3_##CI = q_##CI + r3 * ROWW + gp0;                   \
        float4 a0_##CI = *(const float4*)p0_##CI;                          \
        float4 b0_##CI = *(const float4*)(p0_##CI + 4);                    \
        float4 a1_##CI = *(const float4*)p1_##CI;                          \
        float4 b1_##CI = *(const float4*)(p1_##CI + 4);                    \
        float4 a2_##CI = *(const float4*)p2_##CI;                          \
        float4 b2_##CI = *(const float4*)(p2_##CI + 4);                    \
        float4 a3_##CI = *(const float4*)p3_##CI;                          \
        float4 b3_##CI = *(const float4*)(p3_##CI + 4);

#define PIN2(CI, CJ) asm volatile("" ::                                    \
        "v"(a0_##CI.x), "v"(b0_##CI.x), "v"(a1_##CI.x), "v"(b1_##CI.x),    \
        "v"(a2_##CI.x), "v"(b2_##CI.x), "v"(a3_##CI.x), "v"(b3_##CI.x),    \
        "v"(a0_##CJ.x), "v"(b0_##CJ.x), "v"(a1_##CJ.x), "v"(b1_##CJ.x),    \
        "v"(a2_##CJ.x), "v"(b2_##CJ.x), "v"(a3_##CJ.x), "v"(b3_##CJ.x));

#define NEIGH(A, B, LV, RV) \
        float LV = __shfl_up((B).w, 1) * mL; \
        float RV = __shfl_down((A).x, 1) * mR;

#define ROWACC(A, B, LV, RV, KL, KC, KR) {                                \
        o0 = fmaf((KL), LV,    fmaf((KC), (A).x, fmaf((KR), (A).y, o0))); \
        o1 = fmaf((KL), (A).x, fmaf((KC), (A).y, fmaf((KR), (A).z, o1))); \
        o2 = fmaf((KL), (A).y, fmaf((KC), (A).z, fmaf((KR), (A).w, o2))); \
        o3 = fmaf((KL), (A).z, fmaf((KC), (A).w, fmaf((KR), (B).x, o3))); \
        o4 = fmaf((KL), (A).w, fmaf((KC), (B).x, fmaf((KR), (B).y, o4))); \
        o5 = fmaf((KL), (B).x, fmaf((KC), (B).y, fmaf((KR), (B).z, o5))); \
        o6 = fmaf((KL), (B).y, fmaf((KC), (B).z, fmaf((KR), (B).w, o6))); \
        o7 = fmaf((KL), (B).z, fmaf((KC), (B).w, fmaf((KR), RV,    o7))); }

#define DW_COMP(CI) {                                                  \
        NEIGH(a0_##CI, b0_##CI, l0, rr0) NEIGH(a1_##CI, b1_##CI, l1, rr1) \
        NEIGH(a2_##CI, b2_##CI, l2, rr2) NEIGH(a3_##CI, b3_##CI, l3, rr3) \
        const float* tp = ktaps + (c0 + (CI)) * 12;                    \
        float4 kA = *(const float4*)tp;                                \
        float4 kB = *(const float4*)(tp + 4);                          \
        float  k8v = tp[8];                                            \
        {   /* output row 0: staged 0,1,2 ; top taps masked */         \
            float o0 = 0.f, o1 = 0.f, o2 = 0.f, o3 = 0.f;              \
            float o4 = 0.f, o5 = 0.f, o6 = 0.f, o7 = 0.f;              \
            ROWACC(a0_##CI, b0_##CI, l0, rr0, kA.x * mTop, kA.y * mTop, kA.z * mTop) \
            ROWACC(a1_##CI, b1_##CI, l1, rr1, kA.w, kB.x, kB.y)        \
            ROWACC(a2_##CI, b2_##CI, l2, rr2, kB.z, kB.w, k8v)         \
            bv[0][0][(CI)] = (__bf16)fmaxf(o0, 0.f);                   \
            bv[0][1][(CI)] = (__bf16)fmaxf(o1, 0.f);                   \
            bv[0][2][(CI)] = (__bf16)fmaxf(o2, 0.f);                   \
            bv[0][3][(CI)] = (__bf16)fmaxf(o3, 0.f);                   \
            bv[0][4][(CI)] = (__bf16)fmaxf(o4, 0.f);                   \
            bv[0][5][(CI)] = (__bf16)fmaxf(o5, 0.f);                   \
            bv[0][6][(CI)] = (__bf16)fmaxf(o6, 0.f);                   \
            bv[0][7][(CI)] = (__bf16)fmaxf(o7, 0.f);                   \
        }                                                              \
        {   /* output row 1: staged 1,2,3 ; bottom taps masked */      \
            float o0 = 0.f, o1 = 0.f, o2 = 0.f, o3 = 0.f;              \
            float o4 = 0.f, o5 = 0.f, o6 = 0.f, o7 = 0.f;              \
            ROWACC(a1_##CI, b1_##CI, l1, rr1, kA.x, kA.y, kA.z)        \
            ROWACC(a2_##CI, b2_##CI, l2, rr2, kA.w, kB.x, kB.y)        \
            ROWACC(a3_##CI, b3_##CI, l3, rr3, kB.z * mBot, kB.w * mBot, k8v * mBot) \
            bv[1][0][(CI)] = (__bf16)fmaxf(o0, 0.f);                   \
            bv[1][1][(CI)] = (__bf16)fmaxf(o1, 0.f);                   \
            bv[1][2][(CI)] = (__bf16)fmaxf(o2, 0.f);                   \
            bv[1][3][(CI)] = (__bf16)fmaxf(o3, 0.f);                   \
            bv[1][4][(CI)] = (__bf16)fmaxf(o4, 0.f);                   \
            bv[1][5][(CI)] = (__bf16)fmaxf(o5, 0.f);                   \
            bv[1][6][(CI)] = (__bf16)fmaxf(o6, 0.f);                   \
            bv[1][7][(CI)] = (__bf16)fmaxf(o7, 0.f);                   \
        } }

        // 2-channel-deep pinned pipeline: 16 f4 in flight, then 8 during comp
        DW_LOAD(0) DW_LOAD(1)
        PIN2(0, 1)
        DW_LOAD(2) DW_LOAD(3)
        DW_COMP(0) DW_COMP(1)
        PIN2(2, 3)
        DW_COMP(2) DW_COMP(3)
#undef DW_LOAD
#undef PIN2
#undef DW_COMP
#undef ROWACC
#undef NEIGH

        // store: vblock v = cg>>1 at slot (v ^ pg), half = cg&1
        int slotoff = (((cg >> 1) ^ pg) * 8) + ((cg & 1) * 4);
#define ST(RW, J) *reinterpret_cast<bf16x4*>(&dwT[RW][(pg * 8 + (J)) * 136 + slotoff]) = bv[RW][J];
        ST(0,0) ST(0,1) ST(0,2) ST(0,3) ST(0,4) ST(0,5) ST(0,6) ST(0,7)
        ST(1,0) ST(1,1) ST(1,2) ST(1,3) ST(1,4) ST(1,5) ST(1,6) ST(1,7)
#undef ST
    }
    __syncthreads();
    __builtin_amdgcn_sched_barrier(0);

    // ---------------- Phase 2: 1x1 conv via MFMA (D rows = px), 2 rows ----------------
    {
        int w    = t >> 6;        // wave -> otile (8 otiles of 16 o)
        int lane = t & 63;
        int r = lane & 15;
        int g = lane >> 4;

        bf16x8 bfr[4];
        #pragma unroll
        for (int kc = 0; kc < 4; ++kc)
            bfr[kc] = *reinterpret_cast<const bf16x8*>(
                wfrag + ((size_t)(w * 4 + kc) * 64 + lane) * 8);

        int o = w * 16 + r;
        float bi = conv_b[o];
        float at = att_w[b * 128 + o];

        #pragma unroll 1
        for (int r2 = 0; r2 < 2; ++r2) {
            const ushort* plane = dwT[r2];
            size_t rowoff = (size_t)(b * 128 + o) * PLANE + (size_t)(h0 + r2) * ROWW;
            const float* xrow = x + rowoff;
            float* orow = out + rowoff;

            // prefetch residual x (8 independent float4s hide under MFMA)
            float4 xv[8];
            #pragma unroll
            for (int pt = 0; pt < 8; ++pt)
                xv[pt] = *(const float4*)(xrow + pt * 16 + g * 4);

            f32x4 acc[8];
            #pragma unroll
            for (int pt = 0; pt < 8; ++pt) acc[pt] = (f32x4){0.f, 0.f, 0.f, 0.f};

            #pragma unroll
            for (int pt = 0; pt < 8; ++pt) {
                int px = pt * 16 + r;
                int srow = px * 136;
                int s2 = px >> 3;
                #pragma unroll
                for (int kc = 0; kc < 4; ++kc) {
                    bf16x8 a = *reinterpret_cast<const bf16x8*>(
                        &plane[srow + (((kc * 4 + g) ^ s2) * 8)]);
                    acc[pt] = __builtin_amdgcn_mfma_f32_16x16x32_bf16(a, bfr[kc], acc[pt], 0, 0, 0);
                }
            }

            #pragma unroll
            for (int pt = 0; pt < 8; ++pt) {
                int px = pt * 16 + g * 4;
                float4 ov;
                ov.x = acc[pt][0] + bi + xv[pt].x * at;
                ov.y = acc[pt][1] + bi + xv[pt].y * at;
                ov.z = acc[pt][2] + bi + xv[pt].z * at;
                ov.w = acc[pt][3] + bi + xv[pt].w * at;
                *(float4*)(orow + px) = ov;
            }
        }
    }
}

extern "C" void kernel_launch(void* const* d_in, const int* in_sizes, int n_in,
                              void* d_out, int out_size, void* d_ws, size_t ws_size,
                              hipStream_t stream) {
    (void)in_sizes; (void)n_in; (void)out_size; (void)ws_size;
    const float* x        = (const float*)d_in[0];
    const float* altitude = (const float*)d_in[1];
    const float* W1       = (const float*)d_in[2];
    const float* W2       = (const float*)d_in[3];
    const float* conv_w   = (const float*)d_in[4];
    const float* conv_b   = (const float*)d_in[5];
    const float* ca_w1    = (const float*)d_in[6];
    const float* ca_w2    = (const float*)d_in[7];
    float* out = (float*)d_out;
    float* ws  = (float*)d_ws;

    hipLaunchKernelGGL(precompute_kernel, dim3(32), dim3(256), 0, stream,
                       altitude, W1, W2, ca_w1, ca_w2, conv_w, ws);
    hipLaunchKernelGGL(fused_kernel, dim3(512), dim3(512), 0, stream,
                       x, conv_b, ws, out);
}

// Round 11
// 46.285 us; speedup vs baseline: 1.0733x; 1.0733x over previous
//
#include <hip/hip_runtime.h>
#include <math.h>

typedef __attribute__((ext_vector_type(8))) __bf16 bf16x8;
typedef __attribute__((ext_vector_type(4))) __bf16 bf16x4;
typedef __attribute__((ext_vector_type(4))) float f32x4;

#define PLANE 16384
#define ROWW 128

// ws float layout:
//   [0, 12288)     kern [b][c][12]  (taps 0..8 + pad, f4-aligned)
//   [12288, 13312) att  [b][128]
//   [13312, 21504) wfrag: 16384 ushorts (bf16). B-operand fragments of conv_w^T:
//                  frag[ot(8)][kc(4)][lane(64)][j(8)] = conv_w[ot*16+(lane&15)][kc*32+8*(lane>>4)+j]

__global__ __launch_bounds__(256) void precompute_kernel(
    const float* __restrict__ altitude,
    const float* __restrict__ W1,
    const float* __restrict__ W2,
    const float* __restrict__ ca_w1,
    const float* __restrict__ ca_w2,
    const float* __restrict__ conv_w,
    float* __restrict__ ws)
{
    int bid = blockIdx.x;
    int b = bid >> 2;          // image
    int q = bid & 3;           // quarter of the kern work
    int t = threadIdx.x;
    __shared__ float alt_s[128];
    __shared__ float feat_s[128];
    __shared__ float a1_s[16];

    if (t < 128) alt_s[t] = altitude[b * 128 + t];
    __syncthreads();

    if (t < 128) {
        float s = 0.f;
        const float* wrow = W1 + t * 128;
        for (int j = 0; j < 128; ++j) s += alt_s[j] * wrow[j];
        feat_s[t] = (s >= 0.f) ? s : 0.1f * s;
    } else if (t < 144 && q == 1) {
        int r = t - 128;
        float s = 0.f;
        const float* wrow = ca_w1 + r * 128;
        for (int j = 0; j < 128; ++j) s += alt_s[j] * wrow[j];
        a1_s[r] = (s >= 0.f) ? s : 0.1f * s;
    }
    __syncthreads();

    for (int i = t; i < 288; i += 256) {
        int m = q * 288 + i;
        float s = 0.f;
        const float* wrow = W2 + m * 128;
        for (int j = 0; j < 128; ++j) s += feat_s[j] * wrow[j];
        int c = m / 9, k = m % 9;
        ws[b * 1536 + c * 12 + k] = s;
    }
    if (q == 1 && t < 128) {
        float s = 0.f;
        const float* wrow = ca_w2 + t * 16;
        for (int r = 0; r < 16; ++r) s += a1_s[r] * wrow[r];
        ws[12288 + b * 128 + t] = 1.f / (1.f + expf(-s));
    }
    if (q == 2 && t < 256) {
        int kc   = t >> 6;
        int lane = t & 63;
        int o  = b * 16 + (lane & 15);
        int cb = kc * 32 + 8 * (lane >> 4);
        bf16x8 v;
        #pragma unroll
        for (int j = 0; j < 8; ++j)
            v[j] = (__bf16)conv_w[o * 128 + cb + j];
        ushort* wf = (ushort*)(ws + 13312);
        *reinterpret_cast<bf16x8*>(wf + ((size_t)(b * 4 + kc) * 64 + lane) * 8) = v;
    }
}

// Block = 2 output rows x 128 px x 128 ch. Phase 1: each WAVE processes one
// channel at a time; lane = (row-half, 32 groups of 4 px). Every global load
// is a wave-contiguous 1KB span of a SINGLE channel plane (rows h0-1,h0 or
// h0+1,h0+2 are memory-adjacent). Row redistribution via shfl_xor(32).
__global__ __launch_bounds__(512, 2) void fused_kernel(
    const float* __restrict__ x,
    const float* __restrict__ conv_b,
    const float* __restrict__ ws,
    float* __restrict__ out)
{
    const float* __restrict__ kern_w = ws;
    const float* __restrict__ att_w  = ws + 12288;
    const ushort* __restrict__ wfrag = (const ushort*)(ws + 13312);

    int bid = blockIdx.x;
    int b  = bid & 7;          // XCD swizzle: each XCD streams one batch image
    int rb = bid >> 3;         // row-pair 0..63
    int h0 = rb * 2;

    // two row-planes: dwT[row][px][c] bf16, px stride 136 ushorts;
    // c in 16 vblocks of 8; vblock v at slot (v ^ (px>>3)); phase-2 reads
    // chunk ^ (px>>3) -- same scheme as verified rounds 6-10.
    __shared__ __align__(16) ushort dwT[2][128 * 136];
    __shared__ __align__(16) float ktaps[128 * 12];   // [c][12] taps

    int t = threadIdx.x;
    const float* __restrict__ xb = x + (size_t)b * 128 * PLANE;

    for (int i = t; i < 384; i += 512) {
        float4 v = *(const float4*)(kern_w + b * 1536 + i * 4);
        *(float4*)(&ktaps[i * 4]) = v;
    }
    __syncthreads();

    // ---------------- Phase 1: depthwise 3x3 + ReLU (2 rows) -> dwT ----------------
    {
        int lane = t & 63;
        int wv   = t >> 6;        // wave -> 16 channels wv*16..wv*16+15
        int half = lane >> 5;     // 0/1 = which output row of the pair
        int m32  = lane & 31;     // 4-px group within the full 128-px row
        int p0   = m32 * 4;

        // vA: rows {h0-1, h0} (half 0/1) ; vB: rows {h0+1, h0+2}
        int rA  = half ? h0 : ((rb > 0) ? h0 - 1 : 0);
        int rBr = half ? ((rb < 63) ? h0 + 2 : 127) : (h0 + 1);
        float mTopL = (rb == 0  && half == 0) ? 0.f : 1.f;
        float mBotL = (rb == 63 && half == 1) ? 0.f : 1.f;
        float mLl = (m32 == 0)  ? 0.f : 1.f;
        float mRl = (m32 == 31) ? 0.f : 1.f;

        const float* baseA = xb + rA  * ROWW + p0;
        const float* baseB = xb + rBr * ROWW + p0;

        int c0w = wv * 16;
        int pxg = m32 >> 1;       // == px>>3 for all 4 px of this lane

#define CH_COMP(CB, CI, S0, S1, S2, S3) {                              \
        size_t coff = (size_t)(c0w + (CB) + (CI)) * PLANE;             \
        float4 vA = *(const float4*)(baseA + coff);                    \
        float4 vB = *(const float4*)(baseB + coff);                    \
        float4 tmp;                                                    \
        tmp.x = half ? vA.x : vB.x; tmp.y = half ? vA.y : vB.y;        \
        tmp.z = half ? vA.z : vB.z; tmp.w = half ? vA.w : vB.w;        \
        float4 rM;                                                     \
        rM.x = __shfl_xor(tmp.x, 32); rM.y = __shfl_xor(tmp.y, 32);    \
        rM.z = __shfl_xor(tmp.z, 32); rM.w = __shfl_xor(tmp.w, 32);    \
        const float* tp = ktaps + (c0w + (CB) + (CI)) * 12;            \
        float4 kA = *(const float4*)tp;                                \
        float4 kB = *(const float4*)(tp + 4);                          \
        float  k8v = tp[8];                                            \
        float kU0 = kA.x * mTopL, kU1 = kA.y * mTopL, kU2 = kA.z * mTopL; \
        float kM0 = kA.w,         kM1 = kB.x,         kM2 = kB.y;      \
        float kD0 = kB.z * mBotL, kD1 = kB.w * mBotL, kD2 = k8v * mBotL; \
        float lU = __shfl_up(vA.w, 1) * mLl;                           \
        float rU = __shfl_down(vA.x, 1) * mRl;                         \
        float lM = __shfl_up(rM.w, 1) * mLl;                           \
        float rMv = __shfl_down(rM.x, 1) * mRl;                        \
        float lD = __shfl_up(vB.w, 1) * mLl;                           \
        float rD = __shfl_down(vB.x, 1) * mRl;                         \
        float o0 = fmaf(kU0, lU,   fmaf(kU1, vA.x, fmaf(kU2, vA.y,    \
                   fmaf(kM0, lM,   fmaf(kM1, rM.x, fmaf(kM2, rM.y,    \
                   fmaf(kD0, lD,   fmaf(kD1, vB.x, kD2 * vB.y))))))));\
        float o1 = fmaf(kU0, vA.x, fmaf(kU1, vA.y, fmaf(kU2, vA.z,    \
                   fmaf(kM0, rM.x, fmaf(kM1, rM.y, fmaf(kM2, rM.z,    \
                   fmaf(kD0, vB.x, fmaf(kD1, vB.y, kD2 * vB.z))))))));\
        float o2 = fmaf(kU0, vA.y, fmaf(kU1, vA.z, fmaf(kU2, vA.w,    \
                   fmaf(kM0, rM.y, fmaf(kM1, rM.z, fmaf(kM2, rM.w,    \
                   fmaf(kD0, vB.y, fmaf(kD1, vB.z, kD2 * vB.w))))))));\
        float o3 = fmaf(kU0, vA.z, fmaf(kU1, vA.w, fmaf(kU2, rU,      \
                   fmaf(kM0, rM.z, fmaf(kM1, rM.w, fmaf(kM2, rMv,     \
                   fmaf(kD0, vB.z, fmaf(kD1, vB.w, kD2 * rD))))))));  \
        S0[(CI)] = (__bf16)fmaxf(o0, 0.f);                             \
        S1[(CI)] = (__bf16)fmaxf(o1, 0.f);                             \
        S2[(CI)] = (__bf16)fmaxf(o2, 0.f);                             \
        S3[(CI)] = (__bf16)fmaxf(o3, 0.f); }

#define CH_GROUP(CB) {                                                 \
        bf16x4 s0, s1, s2, s3;                                         \
        CH_COMP(CB, 0, s0, s1, s2, s3)                                 \
        CH_COMP(CB, 1, s0, s1, s2, s3)                                 \
        CH_COMP(CB, 2, s0, s1, s2, s3)                                 \
        CH_COMP(CB, 3, s0, s1, s2, s3)                                 \
        int v_ = (c0w + (CB)) >> 3;                                    \
        int soff_ = ((v_ ^ pxg) * 8) + ((c0w + (CB)) & 4);             \
        ushort* dp_ = dwT[half];                                       \
        *reinterpret_cast<bf16x4*>(&dp_[(p0 + 0) * 136 + soff_]) = s0; \
        *reinterpret_cast<bf16x4*>(&dp_[(p0 + 1) * 136 + soff_]) = s1; \
        *reinterpret_cast<bf16x4*>(&dp_[(p0 + 2) * 136 + soff_]) = s2; \
        *reinterpret_cast<bf16x4*>(&dp_[(p0 + 3) * 136 + soff_]) = s3; }

        CH_GROUP(0) CH_GROUP(4) CH_GROUP(8) CH_GROUP(12)
#undef CH_GROUP
#undef CH_COMP
    }
    __syncthreads();
    __builtin_amdgcn_sched_barrier(0);

    // ---------------- Phase 2: 1x1 conv via MFMA (D rows = px), 2 rows ----------------
    {
        int w    = t >> 6;        // wave -> otile (8 otiles of 16 o)
        int lane = t & 63;
        int r = lane & 15;
        int g = lane >> 4;

        bf16x8 bfr[4];
        #pragma unroll
        for (int kc = 0; kc < 4; ++kc)
            bfr[kc] = *reinterpret_cast<const bf16x8*>(
                wfrag + ((size_t)(w * 4 + kc) * 64 + lane) * 8);

        int o = w * 16 + r;
        float bi = conv_b[o];
        float at = att_w[b * 128 + o];

        #pragma unroll 1
        for (int r2 = 0; r2 < 2; ++r2) {
            const ushort* plane = dwT[r2];
            size_t rowoff = (size_t)(b * 128 + o) * PLANE + (size_t)(h0 + r2) * ROWW;
            const float* xrow = x + rowoff;
            float* orow = out + rowoff;

            // prefetch residual x (8 independent float4s hide under MFMA)
            float4 xv[8];
            #pragma unroll
            for (int pt = 0; pt < 8; ++pt)
                xv[pt] = *(const float4*)(xrow + pt * 16 + g * 4);

            f32x4 acc[8];
            #pragma unroll
            for (int pt = 0; pt < 8; ++pt) acc[pt] = (f32x4){0.f, 0.f, 0.f, 0.f};

            #pragma unroll
            for (int pt = 0; pt < 8; ++pt) {
                int px = pt * 16 + r;
                int srow = px * 136;
                int s2 = px >> 3;
                #pragma unroll
                for (int kc = 0; kc < 4; ++kc) {
                    bf16x8 a = *reinterpret_cast<const bf16x8*>(
                        &plane[srow + (((kc * 4 + g) ^ s2) * 8)]);
                    acc[pt] = __builtin_amdgcn_mfma_f32_16x16x32_bf16(a, bfr[kc], acc[pt], 0, 0, 0);
                }
            }

            #pragma unroll
            for (int pt = 0; pt < 8; ++pt) {
                int px = pt * 16 + g * 4;
                float4 ov;
                ov.x = acc[pt][0] + bi + xv[pt].x * at;
                ov.y = acc[pt][1] + bi + xv[pt].y * at;
                ov.z = acc[pt][2] + bi + xv[pt].z * at;
                ov.w = acc[pt][3] + bi + xv[pt].w * at;
                *(float4*)(orow + px) = ov;
            }
        }
    }
}

extern "C" void kernel_launch(void* const* d_in, const int* in_sizes, int n_in,
                              void* d_out, int out_size, void* d_ws, size_t ws_size,
                              hipStream_t stream) {
    (void)in_sizes; (void)n_in; (void)out_size; (void)ws_size;
    const float* x        = (const float*)d_in[0];
    const float* altitude = (const float*)d_in[1];
    const float* W1       = (const float*)d_in[2];
    const float* W2       = (const float*)d_in[3];
    const float* conv_w   = (const float*)d_in[4];
    const float* conv_b   = (const float*)d_in[5];
    const float* ca_w1    = (const float*)d_in[6];
    const float* ca_w2    = (const float*)d_in[7];
    float* out = (float*)d_out;
    float* ws  = (float*)d_ws;

    hipLaunchKernelGGL(precompute_kernel, dim3(32), dim3(256), 0, stream,
                       altitude, W1, W2, ca_w1, ca_w2, conv_w, ws);
    hipLaunchKernelGGL(fused_kernel, dim3(512), dim3(512), 0, stream,
                       x, conv_b, ws, out);
}